// Round 17
// baseline (230.274 us; speedup 1.0000x reference)
//
#include <hip/hip_runtime.h>
#include <hip/hip_bf16.h>

typedef __bf16 bf16x8 __attribute__((ext_vector_type(8)));
typedef float f32x4 __attribute__((ext_vector_type(4)));
typedef float f32x2 __attribute__((ext_vector_type(2)));
typedef unsigned char u8;

#define G_DIM 128

// ---- helpers ----
__device__ __forceinline__ float bf2f(ushort u) {
  return __uint_as_float(((unsigned int)u) << 16);
}

__device__ __forceinline__ bf16x8 cvt8(float4 f0, float4 f1) {
  bf16x8 v;
  v[0] = (__bf16)f0.x; v[1] = (__bf16)f0.y; v[2] = (__bf16)f0.z; v[3] = (__bf16)f0.w;
  v[4] = (__bf16)f1.x; v[5] = (__bf16)f1.y; v[6] = (__bf16)f1.z; v[7] = (__bf16)f1.w;
  return v;
}

// swizzled ushort index into a row-major [rows][128] bf16 LDS tile.
__device__ __forceinline__ int swz_idx(int row, int kc) {
  return (row * 128 + kc * 8) ^ ((row & 7) << 3);
}

// ---- merged init: W fp32->bf16 pack (blocks 0..71) + segment ranges (blocks 72..) ----
#define WCVT_BLOCKS 72
__global__ void k_init(const float* __restrict__ Wl, const float* __restrict__ Wr,
                       const float* __restrict__ Wih, const float* __restrict__ Whh,
                       const float* __restrict__ Wfc, __bf16* __restrict__ dst,
                       const int* __restrict__ batch, int* __restrict__ seg,
                       int n, int g) {
  if (blockIdx.x < WCVT_BLOCKS) {
    int i = blockIdx.x * blockDim.x + threadIdx.x;
    if (i >= 147456 / 8) return;
    int e = i * 8;
    const float* src; int off;
    if (e < 16384)       { src = Wl;  off = e; }
    else if (e < 32768)  { src = Wr;  off = e - 16384; }
    else if (e < 81920)  { src = Wih; off = e - 32768; }
    else if (e < 131072) { src = Whh; off = e - 81920; }
    else                 { src = Wfc; off = e - 131072; }
    float4 a = ((const float4*)(src + off))[0];
    float4 b = ((const float4*)(src + off))[1];
    *(bf16x8*)(dst + e) = cvt8(a, b);
  } else {
    int i = (blockIdx.x - WCVT_BLOCKS) * blockDim.x + threadIdx.x;
    if (i >= n) return;
    int b = batch[i];
    int prev = (i == 0) ? -1 : batch[i - 1];
    for (int q = prev + 1; q <= b; ++q) seg[q] = i;
    if (i == n - 1) {
      for (int q = b + 1; q <= g; ++q) seg[q] = n;
    }
  }
}

// ---- fused GEMM + band pool. xl = fp8_e4m3(x @ Wl.T + bl); band-exclusive pool
// partial sums; NO atomics. (EXACT R14 version — known good, deterministic) ----
__global__ __launch_bounds__(256, 3) void k_xlgemm(const __bf16* __restrict__ Wbf,
                                                   const float* __restrict__ x,
                                                   const float* __restrict__ bias,
                                                   const int* __restrict__ batch,
                                                   u8* __restrict__ xl8,
                                                   float* __restrict__ pool,
                                                   float* __restrict__ edgebuf,
                                                   int rows, int ntiles) {
  __shared__ __align__(16) ushort sB[128 * 128];  // W, swizzled, persistent
  __shared__ __align__(16) ushort sA[64 * 128];   // x tile (swz); band sub-region reused for fp8 xl
  __shared__ int sBatchE[66];                     // batch[row0-1 .. row0+64]
  const int tid = threadIdx.x;
  const int lane = tid & 63;
  const int wv = tid >> 6;
  const int l15 = lane & 15;
  const int kg = lane >> 4;
  const int r0 = tid >> 4, kc0 = tid & 15;
  const float4 z4 = float4{0.f, 0.f, 0.f, 0.f};

  for (int c = tid; c < 128 * 16; c += 256) {
    int row = c >> 4, kc = c & 15;
    *(bf16x8*)(&sB[swz_idx(row, kc)]) = *(const bf16x8*)(Wbf + (long)row * 128 + kc * 8);
  }
  float bv[8];
  #pragma unroll
  for (int nt = 0; nt < 8; ++nt) bv[nt] = bias[nt * 16 + l15];

  float4 p0 = z4, p1 = z4, p2 = z4, p3 = z4, p4 = z4, p5 = z4, p6 = z4, p7 = z4;
  {
    long row0 = (long)blockIdx.x * 64;
    bool v0 = row0 + r0 < rows, v1 = row0 + r0 + 16 < rows;
    bool v2 = row0 + r0 + 32 < rows, v3 = row0 + r0 + 48 < rows;
    const float4* s0 = (const float4*)(x + (row0 + r0) * 128 + kc0 * 8);
    const float4* s1 = (const float4*)(x + (row0 + r0 + 16) * 128 + kc0 * 8);
    const float4* s2 = (const float4*)(x + (row0 + r0 + 32) * 128 + kc0 * 8);
    const float4* s3 = (const float4*)(x + (row0 + r0 + 48) * 128 + kc0 * 8);
    if (v0) { p0 = s0[0]; p1 = s0[1]; }
    if (v1) { p2 = s1[0]; p3 = s1[1]; }
    if (v2) { p4 = s2[0]; p5 = s2[1]; }
    if (v3) { p6 = s3[0]; p7 = s3[1]; }
  }

  for (int tile = blockIdx.x; tile < ntiles; tile += gridDim.x) {
    const long row0 = (long)tile * 64;
    *(bf16x8*)(&sA[swz_idx(r0, kc0)]) = cvt8(p0, p1);
    *(bf16x8*)(&sA[swz_idx(r0 + 16, kc0)]) = cvt8(p2, p3);
    *(bf16x8*)(&sA[swz_idx(r0 + 32, kc0)]) = cvt8(p4, p5);
    *(bf16x8*)(&sA[swz_idx(r0 + 48, kc0)]) = cvt8(p6, p7);
    if (tid < 66) {
      long idx = row0 - 1 + tid;
      sBatchE[tid] = (idx < 0) ? -3 : (idx < rows ? batch[idx] : -2);
    }
    __syncthreads();

    float4 n0 = z4, n1 = z4, n2 = z4, n3 = z4, n4 = z4, n5 = z4, n6 = z4, n7 = z4;
    {
      int next = tile + gridDim.x;
      if (next < ntiles) {
        long rn = (long)next * 64;
        bool v0 = rn + r0 < rows, v1 = rn + r0 + 16 < rows;
        bool v2 = rn + r0 + 32 < rows, v3 = rn + r0 + 48 < rows;
        const float4* s0 = (const float4*)(x + (rn + r0) * 128 + kc0 * 8);
        const float4* s1 = (const float4*)(x + (rn + r0 + 16) * 128 + kc0 * 8);
        const float4* s2 = (const float4*)(x + (rn + r0 + 32) * 128 + kc0 * 8);
        const float4* s3 = (const float4*)(x + (rn + r0 + 48) * 128 + kc0 * 8);
        if (v0) { n0 = s0[0]; n1 = s0[1]; }
        if (v1) { n2 = s1[0]; n3 = s1[1]; }
        if (v2) { n4 = s2[0]; n5 = s2[1]; }
        if (v3) { n6 = s3[0]; n7 = s3[1]; }
      }
    }

    f32x4 acc[8];
    #pragma unroll
    for (int nt = 0; nt < 8; ++nt) acc[nt] = f32x4{0.f, 0.f, 0.f, 0.f};
    const int mrow = wv * 16 + l15;
    #pragma unroll
    for (int ks = 0; ks < 4; ++ks) {
      bf16x8 af = *(const bf16x8*)(&sA[swz_idx(mrow, ks * 4 + kg)]);
      #pragma unroll
      for (int nt = 0; nt < 8; ++nt) {
        bf16x8 bfr = *(const bf16x8*)(&sB[swz_idx(nt * 16 + l15, ks * 4 + kg)]);
        acc[nt] = __builtin_amdgcn_mfma_f32_16x16x32_bf16(af, bfr, acc[nt], 0, 0, 0);
      }
    }

    // band pool (wave-uniform segment walk, exclusive stores)
    {
      const int rbeg = wv * 16;
      const long band = (long)tile * 4 + wv;
      int r = 0;
      while (r < 16) {
        int g = sBatchE[1 + rbeg + r];
        if (g < 0) break;
        int e = r + 1;
        while (e < 16 && sBatchE[1 + rbeg + e] == g) ++e;
        float s8[8];
        #pragma unroll
        for (int q = 0; q < 8; ++q) s8[q] = 0.f;
        #pragma unroll
        for (int j = 0; j < 4; ++j) {
          int row = kg + 4 * j;
          if (row >= r && row < e) {
            bf16x8 v = *(const bf16x8*)(&sA[swz_idx(rbeg + row, l15)]);
            #pragma unroll
            for (int q = 0; q < 8; ++q) s8[q] += (float)v[q];
          }
        }
        #pragma unroll
        for (int q = 0; q < 8; ++q) {
          s8[q] += __shfl_xor(s8[q], 16, 64);
          s8[q] += __shfl_xor(s8[q], 32, 64);
        }
        bool lext = (r == 0) && (sBatchE[rbeg] == g);
        bool rext = (e == 16) && (sBatchE[1 + rbeg + 16] == g);
        if (kg == 0) {
          float* dst = (!lext && !rext)
              ? (pool + (long)g * 128)
              : (edgebuf + (band * 2 + ((r == 0) ? 0 : 1)) * 128);
          *(float4*)(dst + l15 * 8) = float4{s8[0], s8[1], s8[2], s8[3]};
          *(float4*)(dst + l15 * 8 + 4) = float4{s8[4], s8[5], s8[6], s8[7]};
        }
        r = e;
      }
    }

    // epilogue: fp8 encode into wave's OWN band sub-region, linear bounce stores
    {
      u8* band8 = (u8*)sA + wv * 4096;
      #pragma unroll
      for (int nt = 0; nt < 8; ++nt) {
        int col = nt * 16 + l15;
        #pragma unroll
        for (int j = 0; j < 4; ++j) {
          int lrow = kg * 4 + j;
          float v = acc[nt][j] + bv[nt];
          int enc = __builtin_amdgcn_cvt_pk_fp8_f32(v, v, 0, false);
          band8[lrow * 128 + col] = (u8)(enc & 0xFF);
        }
      }
      #pragma unroll
      for (int t = 0; t < 2; ++t) {
        int g = t * 64 + lane;
        int lrow = g >> 3, chunk = g & 7;
        long grow = row0 + wv * 16 + lrow;
        if (grow < rows) {
          uint4 v = *(const uint4*)(&band8[lrow * 128 + chunk * 16]);
          *(uint4*)(xl8 + grow * 128 + chunk * 16) = v;
        }
      }
    }
    __syncthreads();
    p0 = n0; p1 = n1; p2 = n2; p3 = n3; p4 = n4; p5 = n5; p6 = n6; p7 = n7;
  }
}

// ---- fused pool combine + first Wr GEMM (unchanged) ----
__global__ __launch_bounds__(256) void k_poolgemm(const int* __restrict__ seg,
                                                  const float* __restrict__ edgebuf,
                                                  const float* __restrict__ poolpart,
                                                  const __bf16* __restrict__ W,
                                                  const float* __restrict__ bias,
                                                  float* __restrict__ xr,
                                                  __bf16* __restrict__ cb0, int G) {
  __shared__ __align__(16) ushort sB[128 * 128];
  __shared__ __align__(16) ushort sA[64 * 128];
  const int tid = threadIdx.x;
  const long g0 = (long)blockIdx.x * 64;
  for (int c = tid; c < 128 * 16; c += 256) {
    int row = c >> 4, kc = c & 15;
    *(bf16x8*)(&sB[swz_idx(row, kc)]) = *(const bf16x8*)(W + (long)row * 128 + kc * 8);
  }
  const int rb = tid >> 4, kc = tid & 15;
  #pragma unroll
  for (int q = 0; q < 4; ++q) {
    int gr = rb + q * 16;
    long g = g0 + gr;
    float f[8];
    #pragma unroll
    for (int u = 0; u < 8; ++u) f[u] = 0.f;
    if (g < G) {
      int s = seg[g], e = seg[g + 1];
      if (s < e) {
        int b0 = s >> 4, b1 = (e - 1) >> 4;
        if (b0 == b1) {
          const float4* src = (const float4*)(poolpart + g * 128 + kc * 8);
          float4 u0 = src[0], u1 = src[1];
          f[0] = u0.x; f[1] = u0.y; f[2] = u0.z; f[3] = u0.w;
          f[4] = u1.x; f[5] = u1.y; f[6] = u1.z; f[7] = u1.w;
        } else {
          for (int t = b0; t <= b1; ++t) {
            int slot = (t == b0 && (s > (t << 4))) ? 1 : 0;
            const float4* src = (const float4*)(edgebuf + ((long)t * 2 + slot) * 128 + kc * 8);
            float4 u0 = src[0], u1 = src[1];
            f[0] += u0.x; f[1] += u0.y; f[2] += u0.z; f[3] += u0.w;
            f[4] += u1.x; f[5] += u1.y; f[6] += u1.z; f[7] += u1.w;
          }
        }
      }
      bf16x8 v;
      #pragma unroll
      for (int u = 0; u < 8; ++u) v[u] = (__bf16)fmaxf(f[u], 0.f);
      *(bf16x8*)(&sA[swz_idx(gr, kc)]) = v;
      *(bf16x8*)(cb0 + g * 128 + kc * 8) = v;
    } else {
      bf16x8 v;
      #pragma unroll
      for (int u = 0; u < 8; ++u) v[u] = (__bf16)0.f;
      *(bf16x8*)(&sA[swz_idx(gr, kc)]) = v;
    }
  }
  const int lane = tid & 63;
  const int wv = tid >> 6;
  const int l15 = lane & 15;
  const int kg = lane >> 4;
  __syncthreads();

  f32x4 acc[8];
  #pragma unroll
  for (int nt = 0; nt < 8; ++nt) acc[nt] = f32x4{0.f, 0.f, 0.f, 0.f};
  const int mrow = wv * 16 + l15;
  #pragma unroll
  for (int ks = 0; ks < 4; ++ks) {
    bf16x8 af = *(const bf16x8*)(&sA[swz_idx(mrow, ks * 4 + kg)]);
    #pragma unroll
    for (int nt = 0; nt < 8; ++nt) {
      bf16x8 bfr = *(const bf16x8*)(&sB[swz_idx(nt * 16 + l15, ks * 4 + kg)]);
      acc[nt] = __builtin_amdgcn_mfma_f32_16x16x32_bf16(af, bfr, acc[nt], 0, 0, 0);
    }
  }
  #pragma unroll
  for (int nt = 0; nt < 8; ++nt) {
    int col = nt * 16 + l15;
    float bvv = bias[col];
    #pragma unroll
    for (int j = 0; j < 4; ++j) {
      long r = g0 + wv * 16 + kg * 4 + j;
      if (r < G) xr[r * 128 + col] = acc[nt][j] + bvv;
    }
  }
}

// ---- fused GATv2: graph-per-GROUP (16 lanes own one graph; lane owns 8 dims).
// Rows stream serially 2-at-a-time -> long pipelinable loop, no cross-group
// reduce, fully-coalesced 128B stores. Constant-shift softmax (exact). ----
__global__ __launch_bounds__(256) void k_gat(const u8* __restrict__ xl8,
                                             const float* __restrict__ xr,
                                             const int* __restrict__ seg,
                                             const float* __restrict__ att,
                                             const float* __restrict__ gat_bias,
                                             __bf16* __restrict__ h, int G) {
  const int tid = threadIdx.x;
  const int lane = tid & 63;
  const int li = lane & 15;
  long wid = (long)blockIdx.x * 16 + (tid >> 4);  // group id = graph id
  if (wid >= G) return;
  int s = seg[wid], e = seg[wid + 1];
  int d0 = li * 8;

  float xrv[8], atv[8];
  {
    const float* xrp = xr + wid * G_DIM + d0;
    float4 a0 = *(const float4*)(xrp);
    float4 a1 = *(const float4*)(xrp + 4);
    float4 t0 = *(const float4*)(att + d0);
    float4 t1 = *(const float4*)(att + d0 + 4);
    xrv[0]=a0.x; xrv[1]=a0.y; xrv[2]=a0.z; xrv[3]=a0.w;
    xrv[4]=a1.x; xrv[5]=a1.y; xrv[6]=a1.z; xrv[7]=a1.w;
    atv[0]=t0.x; atv[1]=t0.y; atv[2]=t0.z; atv[3]=t0.w;
    atv[4]=t1.x; atv[5]=t1.y; atv[6]=t1.z; atv[7]=t1.w;
  }

  float den = 0.f;
  float acc[8];
  #pragma unroll
  for (int q = 0; q < 8; ++q) acc[q] = 0.f;

#define GPROC(uu, vv)                                                        \
  {                                                                          \
    f32x2 f01 = __builtin_amdgcn_cvt_pk_f32_fp8((int)(uu).x, false);         \
    f32x2 f23 = __builtin_amdgcn_cvt_pk_f32_fp8((int)(uu).x, true);          \
    f32x2 f45 = __builtin_amdgcn_cvt_pk_f32_fp8((int)(uu).y, false);         \
    f32x2 f67 = __builtin_amdgcn_cvt_pk_f32_fp8((int)(uu).y, true);          \
    float xv[8];                                                             \
    xv[0]=f01[0]; xv[1]=f01[1]; xv[2]=f23[0]; xv[3]=f23[1];                  \
    xv[4]=f45[0]; xv[5]=f45[1]; xv[6]=f67[0]; xv[7]=f67[1];                  \
    float p = 0.f;                                                           \
    _Pragma("unroll") for (int q = 0; q < 8; ++q) {                          \
      float tt = xv[q] + xrv[q];                                             \
      tt = fmaxf(tt, 0.f) + 0.01f * fminf(tt, 0.f);                          \
      p = fmaf(tt, atv[q], p);                                               \
    }                                                                        \
    p += __shfl_xor(p, 1, 64);                                               \
    p += __shfl_xor(p, 2, 64);                                               \
    p += __shfl_xor(p, 4, 64);                                               \
    p += __shfl_xor(p, 8, 64);                                               \
    float w = (vv) ? __expf(p - 4.f) : 0.f;                                  \
    den += w;                                                                \
    _Pragma("unroll") for (int q = 0; q < 8; ++q) acc[q] = fmaf(w, xv[q], acc[q]); \
  }

  const uint2 zu = uint2{0u, 0u};
  for (int i = s; i < e; i += 2) {
    int iB = i + 1;
    bool vB = iB < e;
    uint2 uA = *(const uint2*)(xl8 + (long)i * G_DIM + d0);
    uint2 uB = vB ? *(const uint2*)(xl8 + (long)iB * G_DIM + d0) : zu;
    GPROC(uA, true)
    GPROC(uB, vB)
  }
#undef GPROC

  float inv = (e > s) ? 1.f / den : 0.f;
  bf16x8 o;
  #pragma unroll
  for (int q = 0; q < 8; ++q) {
    float v = acc[q] * inv + gat_bias[d0 + q];
    o[q] = (__bf16)(v > 0.f ? v : __expf(v) - 1.f);  // elu
  }
  *(bf16x8*)((ushort*)h + wid * G_DIM + d0) = o;
}

// ---- fused GRU + next-xr GEMM, 32-row tiles (2 blocks/CU). (EXACT R14) ----
__global__ __launch_bounds__(256) void k_grufuse(const __bf16* __restrict__ h,
                                                 const __bf16* __restrict__ cur,
                                                 const __bf16* __restrict__ W_ih,
                                                 const __bf16* __restrict__ W_hh,
                                                 const float* __restrict__ b_ih,
                                                 const float* __restrict__ b_hh,
                                                 const __bf16* __restrict__ Wnext,
                                                 const float* __restrict__ bnext,
                                                 __bf16* __restrict__ nxt,
                                                 float* __restrict__ xrdst,
                                                 int G, int writeNxt) {
  __shared__ __align__(16) ushort sA1[32 * 128];
  __shared__ __align__(16) ushort sA2[32 * 128];
  __shared__ __align__(16) ushort sW[2][128 * 128];
  const int tid = threadIdx.x;
  const int lane = tid & 63, wv = tid >> 6, l15 = lane & 15, kg = lane >> 4;
  const long row0 = (long)blockIdx.x * 32;
  const int r0w = tid >> 4, kcw = tid & 15;
  const int colb = wv * 32 + l15;

  #pragma unroll
  for (int c0 = 0; c0 < 2; ++c0) {
    int c = tid + c0 * 256;
    int r = c >> 4, kc = c & 15;
    long gr = row0 + r;
    bf16x8 v1, v2;
    if (gr < G) {
      v1 = *(const bf16x8*)(h + gr * 128 + kc * 8);
      v2 = *(const bf16x8*)(cur + gr * 128 + kc * 8);
    } else {
      #pragma unroll
      for (int u = 0; u < 8; ++u) { v1[u] = (__bf16)0.f; v2[u] = (__bf16)0.f; }
    }
    *(bf16x8*)(&sA1[swz_idx(r, kc)]) = v1;
    *(bf16x8*)(&sA2[swz_idx(r, kc)]) = v2;
  }
  {
    const __bf16* wp = W_ih + (long)r0w * 128 + kcw * 8;
    #pragma unroll
    for (int k = 0; k < 8; ++k)
      *(bf16x8*)(&sW[0][swz_idx(r0w + 16 * k, kcw)]) = *(const bf16x8*)(wp + k * 2048);
  }
  __syncthreads();

  float hp[2][2][4];
  #pragma unroll
  for (int rt = 0; rt < 2; ++rt)
    #pragma unroll
    for (int ntl = 0; ntl < 2; ++ntl) {
      int col = colb + ntl * 16;
      #pragma unroll
      for (int j = 0; j < 4; ++j) {
        int row = rt * 16 + kg * 4 + j;
        hp[rt][ntl][j] = bf2f(sA2[swz_idx(row, col >> 3) + (col & 7)]);
      }
    }

  f32x4 rp[2][2], zp[2][2], inn[2][2], hnn[2][2];
  #pragma unroll
  for (int a = 0; a < 2; ++a)
    #pragma unroll
    for (int b = 0; b < 2; ++b) {
      rp[a][b] = f32x4{0.f, 0.f, 0.f, 0.f};
      zp[a][b] = f32x4{0.f, 0.f, 0.f, 0.f};
      inn[a][b] = f32x4{0.f, 0.f, 0.f, 0.f};
      hnn[a][b] = f32x4{0.f, 0.f, 0.f, 0.f};
    }

#define MM(ACC, SAX, WB)                                                      \
  _Pragma("unroll") for (int ks = 0; ks < 4; ++ks) {                          \
    bf16x8 a0 = *(const bf16x8*)(&SAX[swz_idx(l15, ks * 4 + kg)]);            \
    bf16x8 a1 = *(const bf16x8*)(&SAX[swz_idx(16 + l15, ks * 4 + kg)]);       \
    bf16x8 b0 = *(const bf16x8*)(&(WB)[swz_idx(colb, ks * 4 + kg)]);          \
    bf16x8 b1 = *(const bf16x8*)(&(WB)[swz_idx(colb + 16, ks * 4 + kg)]);     \
    ACC[0][0] = __builtin_amdgcn_mfma_f32_16x16x32_bf16(a0, b0, ACC[0][0], 0, 0, 0); \
    ACC[0][1] = __builtin_amdgcn_mfma_f32_16x16x32_bf16(a0, b1, ACC[0][1], 0, 0, 0); \
    ACC[1][0] = __builtin_amdgcn_mfma_f32_16x16x32_bf16(a1, b0, ACC[1][0], 0, 0, 0); \
    ACC[1][1] = __builtin_amdgcn_mfma_f32_16x16x32_bf16(a1, b1, ACC[1][1], 0, 0, 0); \
  }

#define STEP(S, NEXTSRC, ACC, SAX)                                            \
  {                                                                           \
    bf16x8 w0, w1, w2, w3, w4, w5, w6, w7;                                    \
    {                                                                         \
      const __bf16* wp = (NEXTSRC) + (long)r0w * 128 + kcw * 8;               \
      w0 = *(const bf16x8*)(wp + 0 * 2048); w1 = *(const bf16x8*)(wp + 1 * 2048); \
      w2 = *(const bf16x8*)(wp + 2 * 2048); w3 = *(const bf16x8*)(wp + 3 * 2048); \
      w4 = *(const bf16x8*)(wp + 4 * 2048); w5 = *(const bf16x8*)(wp + 5 * 2048); \
      w6 = *(const bf16x8*)(wp + 6 * 2048); w7 = *(const bf16x8*)(wp + 7 * 2048); \
    }                                                                         \
    MM(ACC, SAX, sW[(S) & 1])                                                 \
    {                                                                         \
      ushort* wb = sW[((S) + 1) & 1];                                         \
      *(bf16x8*)(&wb[swz_idx(r0w + 0, kcw)])   = w0;                          \
      *(bf16x8*)(&wb[swz_idx(r0w + 16, kcw)])  = w1;                          \
      *(bf16x8*)(&wb[swz_idx(r0w + 32, kcw)])  = w2;                          \
      *(bf16x8*)(&wb[swz_idx(r0w + 48, kcw)])  = w3;                          \
      *(bf16x8*)(&wb[swz_idx(r0w + 64, kcw)])  = w4;                          \
      *(bf16x8*)(&wb[swz_idx(r0w + 80, kcw)])  = w5;                          \
      *(bf16x8*)(&wb[swz_idx(r0w + 96, kcw)])  = w6;                          \
      *(bf16x8*)(&wb[swz_idx(r0w + 112, kcw)]) = w7;                          \
    }                                                                         \
    __syncthreads();                                                          \
  }

  STEP(0, W_hh,          rp,  sA1)
  STEP(1, W_ih + 16384,  rp,  sA2)
  STEP(2, W_hh + 16384,  zp,  sA1)
  STEP(3, W_ih + 32768,  zp,  sA2)
  STEP(4, W_hh + 32768,  inn, sA1)
  STEP(5, Wnext,         hnn, sA2)
#undef STEP

  float nv[2][2][4];
  #pragma unroll
  for (int ntl = 0; ntl < 2; ++ntl) {
    int col = colb + ntl * 16;
    float bir = b_ih[col], biz = b_ih[col + 128], bin = b_ih[col + 256];
    float bhr = b_hh[col], bhz = b_hh[col + 128], bhn = b_hh[col + 256];
    #pragma unroll
    for (int rt = 0; rt < 2; ++rt)
      #pragma unroll
      for (int j = 0; j < 4; ++j) {
        float rr = 1.f / (1.f + __expf(-(rp[rt][ntl][j] + bir + bhr)));
        float zz = 1.f / (1.f + __expf(-(zp[rt][ntl][j] + biz + bhz)));
        float nn = tanhf(inn[rt][ntl][j] + bin + rr * (hnn[rt][ntl][j] + bhn));
        nv[rt][ntl][j] = fmaxf((1.f - zz) * nn + zz * hp[rt][ntl][j], 0.f);
      }
  }
  #pragma unroll
  for (int rt = 0; rt < 2; ++rt)
    #pragma unroll
    for (int ntl = 0; ntl < 2; ++ntl) {
      int col = colb + ntl * 16;
      #pragma unroll
      for (int j = 0; j < 4; ++j) {
        int row = rt * 16 + kg * 4 + j;
        ushort hb = __builtin_bit_cast(ushort, (__bf16)nv[rt][ntl][j]);
        sA1[swz_idx(row, col >> 3) + (col & 7)] = hb;
        sA2[row * 128 + col] = hb;
      }
    }
  __syncthreads();

  f32x4 acc2[2][2];
  #pragma unroll
  for (int a = 0; a < 2; ++a)
    #pragma unroll
    for (int b = 0; b < 2; ++b) acc2[a][b] = f32x4{0.f, 0.f, 0.f, 0.f};
  MM(acc2, sA1, sW[0])
#undef MM
  #pragma unroll
  for (int ntl = 0; ntl < 2; ++ntl) {
    int col = colb + ntl * 16;
    float bn = bnext[col];
    #pragma unroll
    for (int rt = 0; rt < 2; ++rt)
      #pragma unroll
      for (int j = 0; j < 4; ++j) {
        long r = row0 + rt * 16 + kg * 4 + j;
        if (r < G) xrdst[r * 128 + col] = acc2[rt][ntl][j] + bn;
      }
  }
  if (writeNxt) {
    #pragma unroll
    for (int c0 = 0; c0 < 2; ++c0) {
      int c = tid + c0 * 256;
      int r = c >> 4, chunk = c & 15;
      long gr = row0 + r;
      if (gr < G) {
        bf16x8 v = *(const bf16x8*)(&sA2[r * 128 + chunk * 8]);
        *(bf16x8*)(nxt + gr * 128 + chunk * 8) = v;
      }
    }
  }
}

extern "C" void kernel_launch(void* const* d_in, const int* in_sizes, int n_in,
                              void* d_out, int out_size, void* d_ws, size_t ws_size,
                              hipStream_t stream) {
  const float* x        = (const float*)d_in[0];
  const int*   batch    = (const int*)d_in[1];
  const float* Wl       = (const float*)d_in[2];
  const float* bl       = (const float*)d_in[3];
  const float* Wr       = (const float*)d_in[4];
  const float* br       = (const float*)d_in[5];
  const float* att      = (const float*)d_in[6];
  const float* gat_bias = (const float*)d_in[7];
  const float* W_ih     = (const float*)d_in[8];
  const float* W_hh     = (const float*)d_in[9];
  const float* b_ih     = (const float*)d_in[10];
  const float* b_hh     = (const float*)d_in[11];
  const float* Wfc      = (const float*)d_in[12];
  const float* bfc      = (const float*)d_in[13];
  const int N = in_sizes[1];
  const int G = out_size / G_DIM;
  float* outf = (float*)d_out;

  const int ntiles_big = (N + 63) / 64;
  const long nbands = (long)ntiles_big * 4;

  char* ws = (char*)d_ws;
  size_t off = 0;
  auto alloc = [&](size_t bytes) -> void* {
    void* p = ws + off;
    off = (off + bytes + 255) & ~(size_t)255;
    return p;
  };
  int*    seg      = (int*)alloc(((size_t)G + 1) * sizeof(int));
  float*  poolpart = (float*)alloc((size_t)G * G_DIM * sizeof(float));
  float*  xr       = (float*)alloc((size_t)G * G_DIM * sizeof(float));
  __bf16* hbuf     = (__bf16*)alloc((size_t)G * G_DIM * sizeof(ushort));
  __bf16* cb0      = (__bf16*)alloc((size_t)G * G_DIM * sizeof(ushort));
  __bf16* cb1      = (__bf16*)alloc((size_t)G * G_DIM * sizeof(ushort));
  __bf16* wsW      = (__bf16*)alloc((size_t)147456 * sizeof(ushort));
  float*  edgebuf  = (float*)alloc((size_t)nbands * 2 * G_DIM * sizeof(float));
  u8*     xl8      = (u8*)alloc((size_t)N * G_DIM);
  (void)ws_size; (void)n_in;

  __bf16* Wlb  = wsW;
  __bf16* Wrb  = wsW + 16384;
  __bf16* Wihb = wsW + 32768;
  __bf16* Whhb = wsW + 81920;
  __bf16* Wfcb = wsW + 131072;

  const int nseg = (N + 255) / 256;
  k_init<<<WCVT_BLOCKS + nseg, 256, 0, stream>>>(Wl, Wr, W_ih, W_hh, Wfc, wsW,
                                                 batch, seg, N, G);

  k_xlgemm<<<768, 256, 0, stream>>>(Wlb, x, bl, batch, xl8, poolpart, edgebuf, N, ntiles_big);
  k_poolgemm<<<(G + 63) / 64, 256, 0, stream>>>(seg, edgebuf, poolpart, Wrb, br, xr, cb0, G);

  const int ngat = (G + 15) / 16;
  // t=0
  k_gat<<<ngat, 256, 0, stream>>>(xl8, xr, seg, att, gat_bias, hbuf, G);
  k_grufuse<<<(G + 31) / 32, 256, 0, stream>>>(hbuf, cb0, Wihb, Whhb, b_ih, b_hh,
                                               Wrb, br, cb1, xr, G, 1);
  // t=1
  k_gat<<<ngat, 256, 0, stream>>>(xl8, xr, seg, att, gat_bias, hbuf, G);
  k_grufuse<<<(G + 31) / 32, 256, 0, stream>>>(hbuf, cb1, Wihb, Whhb, b_ih, b_hh,
                                               Wrb, br, cb0, xr, G, 1);
  // t=2: Wnext = Wfc, write final output directly
  k_gat<<<ngat, 256, 0, stream>>>(xl8, xr, seg, att, gat_bias, hbuf, G);
  k_grufuse<<<(G + 31) / 32, 256, 0, stream>>>(hbuf, cb0, Wihb, Whhb, b_ih, b_hh,
                                               Wfcb, bfc, cb1, outf, G, 0);
}

// Round 18
// 216.636 us; speedup vs baseline: 1.0630x; 1.0630x over previous
//
#include <hip/hip_runtime.h>
#include <hip/hip_bf16.h>

typedef __bf16 bf16x8 __attribute__((ext_vector_type(8)));
typedef float f32x4 __attribute__((ext_vector_type(4)));
typedef float f32x2 __attribute__((ext_vector_type(2)));
typedef unsigned char u8;

#define G_DIM 128

// ---- helpers ----
__device__ __forceinline__ float bf2f(ushort u) {
  return __uint_as_float(((unsigned int)u) << 16);
}

__device__ __forceinline__ bf16x8 cvt8(float4 f0, float4 f1) {
  bf16x8 v;
  v[0] = (__bf16)f0.x; v[1] = (__bf16)f0.y; v[2] = (__bf16)f0.z; v[3] = (__bf16)f0.w;
  v[4] = (__bf16)f1.x; v[5] = (__bf16)f1.y; v[6] = (__bf16)f1.z; v[7] = (__bf16)f1.w;
  return v;
}

// swizzled ushort index into a row-major [rows][128] bf16 LDS tile.
__device__ __forceinline__ int swz_idx(int row, int kc) {
  return (row * 128 + kc * 8) ^ ((row & 7) << 3);
}

// ---- merged init: W fp32->bf16 pack (blocks 0..71) + segment ranges (blocks 72..) ----
#define WCVT_BLOCKS 72
__global__ void k_init(const float* __restrict__ Wl, const float* __restrict__ Wr,
                       const float* __restrict__ Wih, const float* __restrict__ Whh,
                       const float* __restrict__ Wfc, __bf16* __restrict__ dst,
                       const int* __restrict__ batch, int* __restrict__ seg,
                       int n, int g) {
  if (blockIdx.x < WCVT_BLOCKS) {
    int i = blockIdx.x * blockDim.x + threadIdx.x;
    if (i >= 147456 / 8) return;
    int e = i * 8;
    const float* src; int off;
    if (e < 16384)       { src = Wl;  off = e; }
    else if (e < 32768)  { src = Wr;  off = e - 16384; }
    else if (e < 81920)  { src = Wih; off = e - 32768; }
    else if (e < 131072) { src = Whh; off = e - 81920; }
    else                 { src = Wfc; off = e - 131072; }
    float4 a = ((const float4*)(src + off))[0];
    float4 b = ((const float4*)(src + off))[1];
    *(bf16x8*)(dst + e) = cvt8(a, b);
  } else {
    int i = (blockIdx.x - WCVT_BLOCKS) * blockDim.x + threadIdx.x;
    if (i >= n) return;
    int b = batch[i];
    int prev = (i == 0) ? -1 : batch[i - 1];
    for (int q = prev + 1; q <= b; ++q) seg[q] = i;
    if (i == n - 1) {
      for (int q = b + 1; q <= g; ++q) seg[q] = n;
    }
  }
}

// ---- fused GEMM + band pool. xl = fp8_e4m3(x @ Wl.T + bl); band-exclusive pool
// partial sums; NO atomics. (EXACT R14 version — known good, deterministic) ----
__global__ __launch_bounds__(256, 3) void k_xlgemm(const __bf16* __restrict__ Wbf,
                                                   const float* __restrict__ x,
                                                   const float* __restrict__ bias,
                                                   const int* __restrict__ batch,
                                                   u8* __restrict__ xl8,
                                                   float* __restrict__ pool,
                                                   float* __restrict__ edgebuf,
                                                   int rows, int ntiles) {
  __shared__ __align__(16) ushort sB[128 * 128];  // W, swizzled, persistent
  __shared__ __align__(16) ushort sA[64 * 128];   // x tile (swz); band sub-region reused for fp8 xl
  __shared__ int sBatchE[66];                     // batch[row0-1 .. row0+64]
  const int tid = threadIdx.x;
  const int lane = tid & 63;
  const int wv = tid >> 6;
  const int l15 = lane & 15;
  const int kg = lane >> 4;
  const int r0 = tid >> 4, kc0 = tid & 15;
  const float4 z4 = float4{0.f, 0.f, 0.f, 0.f};

  for (int c = tid; c < 128 * 16; c += 256) {
    int row = c >> 4, kc = c & 15;
    *(bf16x8*)(&sB[swz_idx(row, kc)]) = *(const bf16x8*)(Wbf + (long)row * 128 + kc * 8);
  }
  float bv[8];
  #pragma unroll
  for (int nt = 0; nt < 8; ++nt) bv[nt] = bias[nt * 16 + l15];

  float4 p0 = z4, p1 = z4, p2 = z4, p3 = z4, p4 = z4, p5 = z4, p6 = z4, p7 = z4;
  {
    long row0 = (long)blockIdx.x * 64;
    bool v0 = row0 + r0 < rows, v1 = row0 + r0 + 16 < rows;
    bool v2 = row0 + r0 + 32 < rows, v3 = row0 + r0 + 48 < rows;
    const float4* s0 = (const float4*)(x + (row0 + r0) * 128 + kc0 * 8);
    const float4* s1 = (const float4*)(x + (row0 + r0 + 16) * 128 + kc0 * 8);
    const float4* s2 = (const float4*)(x + (row0 + r0 + 32) * 128 + kc0 * 8);
    const float4* s3 = (const float4*)(x + (row0 + r0 + 48) * 128 + kc0 * 8);
    if (v0) { p0 = s0[0]; p1 = s0[1]; }
    if (v1) { p2 = s1[0]; p3 = s1[1]; }
    if (v2) { p4 = s2[0]; p5 = s2[1]; }
    if (v3) { p6 = s3[0]; p7 = s3[1]; }
  }

  for (int tile = blockIdx.x; tile < ntiles; tile += gridDim.x) {
    const long row0 = (long)tile * 64;
    *(bf16x8*)(&sA[swz_idx(r0, kc0)]) = cvt8(p0, p1);
    *(bf16x8*)(&sA[swz_idx(r0 + 16, kc0)]) = cvt8(p2, p3);
    *(bf16x8*)(&sA[swz_idx(r0 + 32, kc0)]) = cvt8(p4, p5);
    *(bf16x8*)(&sA[swz_idx(r0 + 48, kc0)]) = cvt8(p6, p7);
    if (tid < 66) {
      long idx = row0 - 1 + tid;
      sBatchE[tid] = (idx < 0) ? -3 : (idx < rows ? batch[idx] : -2);
    }
    __syncthreads();

    float4 n0 = z4, n1 = z4, n2 = z4, n3 = z4, n4 = z4, n5 = z4, n6 = z4, n7 = z4;
    {
      int next = tile + gridDim.x;
      if (next < ntiles) {
        long rn = (long)next * 64;
        bool v0 = rn + r0 < rows, v1 = rn + r0 + 16 < rows;
        bool v2 = rn + r0 + 32 < rows, v3 = rn + r0 + 48 < rows;
        const float4* s0 = (const float4*)(x + (rn + r0) * 128 + kc0 * 8);
        const float4* s1 = (const float4*)(x + (rn + r0 + 16) * 128 + kc0 * 8);
        const float4* s2 = (const float4*)(x + (rn + r0 + 32) * 128 + kc0 * 8);
        const float4* s3 = (const float4*)(x + (rn + r0 + 48) * 128 + kc0 * 8);
        if (v0) { n0 = s0[0]; n1 = s0[1]; }
        if (v1) { n2 = s1[0]; n3 = s1[1]; }
        if (v2) { n4 = s2[0]; n5 = s2[1]; }
        if (v3) { n6 = s3[0]; n7 = s3[1]; }
      }
    }

    f32x4 acc[8];
    #pragma unroll
    for (int nt = 0; nt < 8; ++nt) acc[nt] = f32x4{0.f, 0.f, 0.f, 0.f};
    const int mrow = wv * 16 + l15;
    #pragma unroll
    for (int ks = 0; ks < 4; ++ks) {
      bf16x8 af = *(const bf16x8*)(&sA[swz_idx(mrow, ks * 4 + kg)]);
      #pragma unroll
      for (int nt = 0; nt < 8; ++nt) {
        bf16x8 bfr = *(const bf16x8*)(&sB[swz_idx(nt * 16 + l15, ks * 4 + kg)]);
        acc[nt] = __builtin_amdgcn_mfma_f32_16x16x32_bf16(af, bfr, acc[nt], 0, 0, 0);
      }
    }

    // band pool (wave-uniform segment walk, exclusive stores)
    {
      const int rbeg = wv * 16;
      const long band = (long)tile * 4 + wv;
      int r = 0;
      while (r < 16) {
        int g = sBatchE[1 + rbeg + r];
        if (g < 0) break;
        int e = r + 1;
        while (e < 16 && sBatchE[1 + rbeg + e] == g) ++e;
        float s8[8];
        #pragma unroll
        for (int q = 0; q < 8; ++q) s8[q] = 0.f;
        #pragma unroll
        for (int j = 0; j < 4; ++j) {
          int row = kg + 4 * j;
          if (row >= r && row < e) {
            bf16x8 v = *(const bf16x8*)(&sA[swz_idx(rbeg + row, l15)]);
            #pragma unroll
            for (int q = 0; q < 8; ++q) s8[q] += (float)v[q];
          }
        }
        #pragma unroll
        for (int q = 0; q < 8; ++q) {
          s8[q] += __shfl_xor(s8[q], 16, 64);
          s8[q] += __shfl_xor(s8[q], 32, 64);
        }
        bool lext = (r == 0) && (sBatchE[rbeg] == g);
        bool rext = (e == 16) && (sBatchE[1 + rbeg + 16] == g);
        if (kg == 0) {
          float* dst = (!lext && !rext)
              ? (pool + (long)g * 128)
              : (edgebuf + (band * 2 + ((r == 0) ? 0 : 1)) * 128);
          *(float4*)(dst + l15 * 8) = float4{s8[0], s8[1], s8[2], s8[3]};
          *(float4*)(dst + l15 * 8 + 4) = float4{s8[4], s8[5], s8[6], s8[7]};
        }
        r = e;
      }
    }

    // epilogue: fp8 encode into wave's OWN band sub-region, linear bounce stores
    {
      u8* band8 = (u8*)sA + wv * 4096;
      #pragma unroll
      for (int nt = 0; nt < 8; ++nt) {
        int col = nt * 16 + l15;
        #pragma unroll
        for (int j = 0; j < 4; ++j) {
          int lrow = kg * 4 + j;
          float v = acc[nt][j] + bv[nt];
          int enc = __builtin_amdgcn_cvt_pk_fp8_f32(v, v, 0, false);
          band8[lrow * 128 + col] = (u8)(enc & 0xFF);
        }
      }
      #pragma unroll
      for (int t = 0; t < 2; ++t) {
        int g = t * 64 + lane;
        int lrow = g >> 3, chunk = g & 7;
        long grow = row0 + wv * 16 + lrow;
        if (grow < rows) {
          uint4 v = *(const uint4*)(&band8[lrow * 128 + chunk * 16]);
          *(uint4*)(xl8 + grow * 128 + chunk * 16) = v;
        }
      }
    }
    __syncthreads();
    p0 = n0; p1 = n1; p2 = n2; p3 = n3; p4 = n4; p5 = n5; p6 = n6; p7 = n7;
  }
}

// ---- fused pool combine + first Wr GEMM (unchanged) ----
__global__ __launch_bounds__(256) void k_poolgemm(const int* __restrict__ seg,
                                                  const float* __restrict__ edgebuf,
                                                  const float* __restrict__ poolpart,
                                                  const __bf16* __restrict__ W,
                                                  const float* __restrict__ bias,
                                                  float* __restrict__ xr,
                                                  __bf16* __restrict__ cb0, int G) {
  __shared__ __align__(16) ushort sB[128 * 128];
  __shared__ __align__(16) ushort sA[64 * 128];
  const int tid = threadIdx.x;
  const long g0 = (long)blockIdx.x * 64;
  for (int c = tid; c < 128 * 16; c += 256) {
    int row = c >> 4, kc = c & 15;
    *(bf16x8*)(&sB[swz_idx(row, kc)]) = *(const bf16x8*)(W + (long)row * 128 + kc * 8);
  }
  const int rb = tid >> 4, kc = tid & 15;
  #pragma unroll
  for (int q = 0; q < 4; ++q) {
    int gr = rb + q * 16;
    long g = g0 + gr;
    float f[8];
    #pragma unroll
    for (int u = 0; u < 8; ++u) f[u] = 0.f;
    if (g < G) {
      int s = seg[g], e = seg[g + 1];
      if (s < e) {
        int b0 = s >> 4, b1 = (e - 1) >> 4;
        if (b0 == b1) {
          const float4* src = (const float4*)(poolpart + g * 128 + kc * 8);
          float4 u0 = src[0], u1 = src[1];
          f[0] = u0.x; f[1] = u0.y; f[2] = u0.z; f[3] = u0.w;
          f[4] = u1.x; f[5] = u1.y; f[6] = u1.z; f[7] = u1.w;
        } else {
          for (int t = b0; t <= b1; ++t) {
            int slot = (t == b0 && (s > (t << 4))) ? 1 : 0;
            const float4* src = (const float4*)(edgebuf + ((long)t * 2 + slot) * 128 + kc * 8);
            float4 u0 = src[0], u1 = src[1];
            f[0] += u0.x; f[1] += u0.y; f[2] += u0.z; f[3] += u0.w;
            f[4] += u1.x; f[5] += u1.y; f[6] += u1.z; f[7] += u1.w;
          }
        }
      }
      bf16x8 v;
      #pragma unroll
      for (int u = 0; u < 8; ++u) v[u] = (__bf16)fmaxf(f[u], 0.f);
      *(bf16x8*)(&sA[swz_idx(gr, kc)]) = v;
      *(bf16x8*)(cb0 + g * 128 + kc * 8) = v;
    } else {
      bf16x8 v;
      #pragma unroll
      for (int u = 0; u < 8; ++u) v[u] = (__bf16)0.f;
      *(bf16x8*)(&sA[swz_idx(gr, kc)]) = v;
    }
  }
  const int lane = tid & 63;
  const int wv = tid >> 6;
  const int l15 = lane & 15;
  const int kg = lane >> 4;
  __syncthreads();

  f32x4 acc[8];
  #pragma unroll
  for (int nt = 0; nt < 8; ++nt) acc[nt] = f32x4{0.f, 0.f, 0.f, 0.f};
  const int mrow = wv * 16 + l15;
  #pragma unroll
  for (int ks = 0; ks < 4; ++ks) {
    bf16x8 af = *(const bf16x8*)(&sA[swz_idx(mrow, ks * 4 + kg)]);
    #pragma unroll
    for (int nt = 0; nt < 8; ++nt) {
      bf16x8 bfr = *(const bf16x8*)(&sB[swz_idx(nt * 16 + l15, ks * 4 + kg)]);
      acc[nt] = __builtin_amdgcn_mfma_f32_16x16x32_bf16(af, bfr, acc[nt], 0, 0, 0);
    }
  }
  #pragma unroll
  for (int nt = 0; nt < 8; ++nt) {
    int col = nt * 16 + l15;
    float bvv = bias[col];
    #pragma unroll
    for (int j = 0; j < 4; ++j) {
      long r = g0 + wv * 16 + kg * 4 + j;
      if (r < G) xr[r * 128 + col] = acc[nt][j] + bvv;
    }
  }
}

// ---- fused GATv2: constant-shift softmax, per-group den, fp8 xl decode.
// 16 rows/iteration: 4 raw loads in flight (A,B,C,D), sequential decode. ----
__global__ __launch_bounds__(256) void k_gat(const u8* __restrict__ xl8,
                                             const float* __restrict__ xr,
                                             const int* __restrict__ seg,
                                             const float* __restrict__ att,
                                             const float* __restrict__ gat_bias,
                                             __bf16* __restrict__ h, int G) {
  int wid = (blockIdx.x << 2) + (threadIdx.x >> 6);
  if (wid >= G) return;
  int lane = threadIdx.x & 63;
  int grp = lane >> 4, li = lane & 15;
  int s = seg[wid], e = seg[wid + 1];
  int d0 = li * 8;

  const float* xrp = xr + (long)wid * G_DIM + d0;
  float xrv[8], atv[8];
  {
    float4 a0 = *(const float4*)(xrp);
    float4 a1 = *(const float4*)(xrp + 4);
    float4 t0 = *(const float4*)(att + d0);
    float4 t1 = *(const float4*)(att + d0 + 4);
    xrv[0]=a0.x; xrv[1]=a0.y; xrv[2]=a0.z; xrv[3]=a0.w;
    xrv[4]=a1.x; xrv[5]=a1.y; xrv[6]=a1.z; xrv[7]=a1.w;
    atv[0]=t0.x; atv[1]=t0.y; atv[2]=t0.z; atv[3]=t0.w;
    atv[4]=t1.x; atv[5]=t1.y; atv[6]=t1.z; atv[7]=t1.w;
  }

  float den = 0.f;
  float acc[8];
  #pragma unroll
  for (int q = 0; q < 8; ++q) acc[q] = 0.f;

#define GPROC(uu, vv)                                                        \
  {                                                                          \
    f32x2 f01 = __builtin_amdgcn_cvt_pk_f32_fp8((int)(uu).x, false);         \
    f32x2 f23 = __builtin_amdgcn_cvt_pk_f32_fp8((int)(uu).x, true);          \
    f32x2 f45 = __builtin_amdgcn_cvt_pk_f32_fp8((int)(uu).y, false);         \
    f32x2 f67 = __builtin_amdgcn_cvt_pk_f32_fp8((int)(uu).y, true);          \
    float xv[8];                                                             \
    xv[0]=f01[0]; xv[1]=f01[1]; xv[2]=f23[0]; xv[3]=f23[1];                  \
    xv[4]=f45[0]; xv[5]=f45[1]; xv[6]=f67[0]; xv[7]=f67[1];                  \
    float p = 0.f;                                                           \
    _Pragma("unroll") for (int q = 0; q < 8; ++q) {                          \
      float tt = xv[q] + xrv[q];                                             \
      tt = fmaxf(tt, 0.f) + 0.01f * fminf(tt, 0.f);                          \
      p = fmaf(tt, atv[q], p);                                               \
    }                                                                        \
    p += __shfl_xor(p, 1, 64);                                               \
    p += __shfl_xor(p, 2, 64);                                               \
    p += __shfl_xor(p, 4, 64);                                               \
    p += __shfl_xor(p, 8, 64);                                               \
    float w = (vv) ? __expf(p - 4.f) : 0.f;                                  \
    den += w;                                                                \
    _Pragma("unroll") for (int q = 0; q < 8; ++q) acc[q] = fmaf(w, xv[q], acc[q]); \
  }

  const uint2 zu = uint2{0u, 0u};
  for (int base = s; base < e; base += 16) {
    int iA = base + grp;
    int iB = iA + 4;
    int iC = iA + 8;
    int iD = iA + 12;
    bool vA = iA < e, vB = iB < e, vC = iC < e, vD = iD < e;
    uint2 uA = vA ? *(const uint2*)(xl8 + (long)iA * G_DIM + d0) : zu;
    uint2 uB = vB ? *(const uint2*)(xl8 + (long)iB * G_DIM + d0) : zu;
    uint2 uC = vC ? *(const uint2*)(xl8 + (long)iC * G_DIM + d0) : zu;
    uint2 uD = vD ? *(const uint2*)(xl8 + (long)iD * G_DIM + d0) : zu;
    GPROC(uA, vA)
    GPROC(uB, vB)
    GPROC(uC, vC)
    GPROC(uD, vD)
  }
#undef GPROC

  den += __shfl_xor(den, 16, 64);
  den += __shfl_xor(den, 32, 64);
  #pragma unroll
  for (int q = 0; q < 8; ++q) {
    acc[q] += __shfl_xor(acc[q], 16, 64);
    acc[q] += __shfl_xor(acc[q], 32, 64);
  }
  if (grp == 0) {
    float inv = (e > s) ? 1.f / den : 0.f;
    bf16x8 o;
    #pragma unroll
    for (int q = 0; q < 8; ++q) {
      float v = acc[q] * inv + gat_bias[d0 + q];
      o[q] = (__bf16)(v > 0.f ? v : __expf(v) - 1.f);  // elu
    }
    *(bf16x8*)((ushort*)h + (long)wid * G_DIM + d0) = o;
  }
}

// ---- fused GRU + next-xr GEMM, 32-row tiles (2 blocks/CU). (EXACT R14) ----
__global__ __launch_bounds__(256) void k_grufuse(const __bf16* __restrict__ h,
                                                 const __bf16* __restrict__ cur,
                                                 const __bf16* __restrict__ W_ih,
                                                 const __bf16* __restrict__ W_hh,
                                                 const float* __restrict__ b_ih,
                                                 const float* __restrict__ b_hh,
                                                 const __bf16* __restrict__ Wnext,
                                                 const float* __restrict__ bnext,
                                                 __bf16* __restrict__ nxt,
                                                 float* __restrict__ xrdst,
                                                 int G, int writeNxt) {
  __shared__ __align__(16) ushort sA1[32 * 128];
  __shared__ __align__(16) ushort sA2[32 * 128];
  __shared__ __align__(16) ushort sW[2][128 * 128];
  const int tid = threadIdx.x;
  const int lane = tid & 63, wv = tid >> 6, l15 = lane & 15, kg = lane >> 4;
  const long row0 = (long)blockIdx.x * 32;
  const int r0w = tid >> 4, kcw = tid & 15;
  const int colb = wv * 32 + l15;

  #pragma unroll
  for (int c0 = 0; c0 < 2; ++c0) {
    int c = tid + c0 * 256;
    int r = c >> 4, kc = c & 15;
    long gr = row0 + r;
    bf16x8 v1, v2;
    if (gr < G) {
      v1 = *(const bf16x8*)(h + gr * 128 + kc * 8);
      v2 = *(const bf16x8*)(cur + gr * 128 + kc * 8);
    } else {
      #pragma unroll
      for (int u = 0; u < 8; ++u) { v1[u] = (__bf16)0.f; v2[u] = (__bf16)0.f; }
    }
    *(bf16x8*)(&sA1[swz_idx(r, kc)]) = v1;
    *(bf16x8*)(&sA2[swz_idx(r, kc)]) = v2;
  }
  {
    const __bf16* wp = W_ih + (long)r0w * 128 + kcw * 8;
    #pragma unroll
    for (int k = 0; k < 8; ++k)
      *(bf16x8*)(&sW[0][swz_idx(r0w + 16 * k, kcw)]) = *(const bf16x8*)(wp + k * 2048);
  }
  __syncthreads();

  float hp[2][2][4];
  #pragma unroll
  for (int rt = 0; rt < 2; ++rt)
    #pragma unroll
    for (int ntl = 0; ntl < 2; ++ntl) {
      int col = colb + ntl * 16;
      #pragma unroll
      for (int j = 0; j < 4; ++j) {
        int row = rt * 16 + kg * 4 + j;
        hp[rt][ntl][j] = bf2f(sA2[swz_idx(row, col >> 3) + (col & 7)]);
      }
    }

  f32x4 rp[2][2], zp[2][2], inn[2][2], hnn[2][2];
  #pragma unroll
  for (int a = 0; a < 2; ++a)
    #pragma unroll
    for (int b = 0; b < 2; ++b) {
      rp[a][b] = f32x4{0.f, 0.f, 0.f, 0.f};
      zp[a][b] = f32x4{0.f, 0.f, 0.f, 0.f};
      inn[a][b] = f32x4{0.f, 0.f, 0.f, 0.f};
      hnn[a][b] = f32x4{0.f, 0.f, 0.f, 0.f};
    }

#define MM(ACC, SAX, WB)                                                      \
  _Pragma("unroll") for (int ks = 0; ks < 4; ++ks) {                          \
    bf16x8 a0 = *(const bf16x8*)(&SAX[swz_idx(l15, ks * 4 + kg)]);            \
    bf16x8 a1 = *(const bf16x8*)(&SAX[swz_idx(16 + l15, ks * 4 + kg)]);       \
    bf16x8 b0 = *(const bf16x8*)(&(WB)[swz_idx(colb, ks * 4 + kg)]);          \
    bf16x8 b1 = *(const bf16x8*)(&(WB)[swz_idx(colb + 16, ks * 4 + kg)]);     \
    ACC[0][0] = __builtin_amdgcn_mfma_f32_16x16x32_bf16(a0, b0, ACC[0][0], 0, 0, 0); \
    ACC[0][1] = __builtin_amdgcn_mfma_f32_16x16x32_bf16(a0, b1, ACC[0][1], 0, 0, 0); \
    ACC[1][0] = __builtin_amdgcn_mfma_f32_16x16x32_bf16(a1, b0, ACC[1][0], 0, 0, 0); \
    ACC[1][1] = __builtin_amdgcn_mfma_f32_16x16x32_bf16(a1, b1, ACC[1][1], 0, 0, 0); \
  }

#define STEP(S, NEXTSRC, ACC, SAX)                                            \
  {                                                                           \
    bf16x8 w0, w1, w2, w3, w4, w5, w6, w7;                                    \
    {                                                                         \
      const __bf16* wp = (NEXTSRC) + (long)r0w * 128 + kcw * 8;               \
      w0 = *(const bf16x8*)(wp + 0 * 2048); w1 = *(const bf16x8*)(wp + 1 * 2048); \
      w2 = *(const bf16x8*)(wp + 2 * 2048); w3 = *(const bf16x8*)(wp + 3 * 2048); \
      w4 = *(const bf16x8*)(wp + 4 * 2048); w5 = *(const bf16x8*)(wp + 5 * 2048); \
      w6 = *(const bf16x8*)(wp + 6 * 2048); w7 = *(const bf16x8*)(wp + 7 * 2048); \
    }                                                                         \
    MM(ACC, SAX, sW[(S) & 1])                                                 \
    {                                                                         \
      ushort* wb = sW[((S) + 1) & 1];                                         \
      *(bf16x8*)(&wb[swz_idx(r0w + 0, kcw)])   = w0;                          \
      *(bf16x8*)(&wb[swz_idx(r0w + 16, kcw)])  = w1;                          \
      *(bf16x8*)(&wb[swz_idx(r0w + 32, kcw)])  = w2;                          \
      *(bf16x8*)(&wb[swz_idx(r0w + 48, kcw)])  = w3;                          \
      *(bf16x8*)(&wb[swz_idx(r0w + 64, kcw)])  = w4;                          \
      *(bf16x8*)(&wb[swz_idx(r0w + 80, kcw)])  = w5;                          \
      *(bf16x8*)(&wb[swz_idx(r0w + 96, kcw)])  = w6;                          \
      *(bf16x8*)(&wb[swz_idx(r0w + 112, kcw)]) = w7;                          \
    }                                                                         \
    __syncthreads();                                                          \
  }

  STEP(0, W_hh,          rp,  sA1)
  STEP(1, W_ih + 16384,  rp,  sA2)
  STEP(2, W_hh + 16384,  zp,  sA1)
  STEP(3, W_ih + 32768,  zp,  sA2)
  STEP(4, W_hh + 32768,  inn, sA1)
  STEP(5, Wnext,         hnn, sA2)
#undef STEP

  float nv[2][2][4];
  #pragma unroll
  for (int ntl = 0; ntl < 2; ++ntl) {
    int col = colb + ntl * 16;
    float bir = b_ih[col], biz = b_ih[col + 128], bin = b_ih[col + 256];
    float bhr = b_hh[col], bhz = b_hh[col + 128], bhn = b_hh[col + 256];
    #pragma unroll
    for (int rt = 0; rt < 2; ++rt)
      #pragma unroll
      for (int j = 0; j < 4; ++j) {
        float rr = 1.f / (1.f + __expf(-(rp[rt][ntl][j] + bir + bhr)));
        float zz = 1.f / (1.f + __expf(-(zp[rt][ntl][j] + biz + bhz)));
        float nn = tanhf(inn[rt][ntl][j] + bin + rr * (hnn[rt][ntl][j] + bhn));
        nv[rt][ntl][j] = fmaxf((1.f - zz) * nn + zz * hp[rt][ntl][j], 0.f);
      }
  }
  #pragma unroll
  for (int rt = 0; rt < 2; ++rt)
    #pragma unroll
    for (int ntl = 0; ntl < 2; ++ntl) {
      int col = colb + ntl * 16;
      #pragma unroll
      for (int j = 0; j < 4; ++j) {
        int row = rt * 16 + kg * 4 + j;
        ushort hb = __builtin_bit_cast(ushort, (__bf16)nv[rt][ntl][j]);
        sA1[swz_idx(row, col >> 3) + (col & 7)] = hb;
        sA2[row * 128 + col] = hb;
      }
    }
  __syncthreads();

  f32x4 acc2[2][2];
  #pragma unroll
  for (int a = 0; a < 2; ++a)
    #pragma unroll
    for (int b = 0; b < 2; ++b) acc2[a][b] = f32x4{0.f, 0.f, 0.f, 0.f};
  MM(acc2, sA1, sW[0])
#undef MM
  #pragma unroll
  for (int ntl = 0; ntl < 2; ++ntl) {
    int col = colb + ntl * 16;
    float bn = bnext[col];
    #pragma unroll
    for (int rt = 0; rt < 2; ++rt)
      #pragma unroll
      for (int j = 0; j < 4; ++j) {
        long r = row0 + rt * 16 + kg * 4 + j;
        if (r < G) xrdst[r * 128 + col] = acc2[rt][ntl][j] + bn;
      }
  }
  if (writeNxt) {
    #pragma unroll
    for (int c0 = 0; c0 < 2; ++c0) {
      int c = tid + c0 * 256;
      int r = c >> 4, chunk = c & 15;
      long gr = row0 + r;
      if (gr < G) {
        bf16x8 v = *(const bf16x8*)(&sA2[r * 128 + chunk * 8]);
        *(bf16x8*)(nxt + gr * 128 + chunk * 8) = v;
      }
    }
  }
}

extern "C" void kernel_launch(void* const* d_in, const int* in_sizes, int n_in,
                              void* d_out, int out_size, void* d_ws, size_t ws_size,
                              hipStream_t stream) {
  const float* x        = (const float*)d_in[0];
  const int*   batch    = (const int*)d_in[1];
  const float* Wl       = (const float*)d_in[2];
  const float* bl       = (const float*)d_in[3];
  const float* Wr       = (const float*)d_in[4];
  const float* br       = (const float*)d_in[5];
  const float* att      = (const float*)d_in[6];
  const float* gat_bias = (const float*)d_in[7];
  const float* W_ih     = (const float*)d_in[8];
  const float* W_hh     = (const float*)d_in[9];
  const float* b_ih     = (const float*)d_in[10];
  const float* b_hh     = (const float*)d_in[11];
  const float* Wfc      = (const float*)d_in[12];
  const float* bfc      = (const float*)d_in[13];
  const int N = in_sizes[1];
  const int G = out_size / G_DIM;
  float* outf = (float*)d_out;

  const int ntiles_big = (N + 63) / 64;
  const long nbands = (long)ntiles_big * 4;

  char* ws = (char*)d_ws;
  size_t off = 0;
  auto alloc = [&](size_t bytes) -> void* {
    void* p = ws + off;
    off = (off + bytes + 255) & ~(size_t)255;
    return p;
  };
  int*    seg      = (int*)alloc(((size_t)G + 1) * sizeof(int));
  float*  poolpart = (float*)alloc((size_t)G * G_DIM * sizeof(float));
  float*  xr       = (float*)alloc((size_t)G * G_DIM * sizeof(float));
  __bf16* hbuf     = (__bf16*)alloc((size_t)G * G_DIM * sizeof(ushort));
  __bf16* cb0      = (__bf16*)alloc((size_t)G * G_DIM * sizeof(ushort));
  __bf16* cb1      = (__bf16*)alloc((size_t)G * G_DIM * sizeof(ushort));
  __bf16* wsW      = (__bf16*)alloc((size_t)147456 * sizeof(ushort));
  float*  edgebuf  = (float*)alloc((size_t)nbands * 2 * G_DIM * sizeof(float));
  u8*     xl8      = (u8*)alloc((size_t)N * G_DIM);
  (void)ws_size; (void)n_in;

  __bf16* Wlb  = wsW;
  __bf16* Wrb  = wsW + 16384;
  __bf16* Wihb = wsW + 32768;
  __bf16* Whhb = wsW + 81920;
  __bf16* Wfcb = wsW + 131072;

  const int nseg = (N + 255) / 256;
  k_init<<<WCVT_BLOCKS + nseg, 256, 0, stream>>>(Wl, Wr, W_ih, W_hh, Wfc, wsW,
                                                 batch, seg, N, G);

  k_xlgemm<<<768, 256, 0, stream>>>(Wlb, x, bl, batch, xl8, poolpart, edgebuf, N, ntiles_big);
  k_poolgemm<<<(G + 63) / 64, 256, 0, stream>>>(seg, edgebuf, poolpart, Wrb, br, xr, cb0, G);

  // t=0
  k_gat<<<(G + 3) / 4, 256, 0, stream>>>(xl8, xr, seg, att, gat_bias, hbuf, G);
  k_grufuse<<<(G + 31) / 32, 256, 0, stream>>>(hbuf, cb0, Wihb, Whhb, b_ih, b_hh,
                                               Wrb, br, cb1, xr, G, 1);
  // t=1
  k_gat<<<(G + 3) / 4, 256, 0, stream>>>(xl8, xr, seg, att, gat_bias, hbuf, G);
  k_grufuse<<<(G + 31) / 32, 256, 0, stream>>>(hbuf, cb1, Wihb, Whhb, b_ih, b_hh,
                                               Wrb, br, cb0, xr, G, 1);
  // t=2: Wnext = Wfc, write final output directly
  k_gat<<<(G + 3) / 4, 256, 0, stream>>>(xl8, xr, seg, att, gat_bias, hbuf, G);
  k_grufuse<<<(G + 31) / 32, 256, 0, stream>>>(hbuf, cb0, Wihb, Whhb, b_ih, b_hh,
                                               Wfcb, bfc, cb1, outf, G, 0);
}